// Round 3
// baseline (299.521 us; speedup 1.0000x reference)
//
#include <hip/hip_runtime.h>
#include <stdint.h>

// BinarizeConv2dSDP: out = conv3x3(sign(x), sign(M), pad=1) * Alpha[o]
// R7: GEMM restructured to 2-phase pipeline (T3-minimum):
//   - Al double-buffered; stage(t+1) issued BEFORE compute(t); ONE barrier
//     per K-step (implicit vmcnt(0) drain lands after ~1650cy of MFMA).
//   - Weights moved LDS -> registers: wpk re-laid out (pack_w) so each lane's
//     32B A-operand is contiguous; 12 dwordx4 L2-resident loads/step (48 VGPR).
//     Channel placement af.l[ks] <-> c0+16ks+8hb+0..7 preserved => bit-identical.
//   - XCD-bijective block swizzle (832 = 8*104): ot-pairs share A-tile on one XCD.
// binarize_act unchanged (verified absmax 0.0).

typedef __attribute__((ext_vector_type(16))) float floatx16;
typedef __attribute__((ext_vector_type(8)))  int   intx8;

#define N_IMG 32
#define C_IN  256
#define O_OUT 256
#define HP 58
#define WP 58
#define GPI 3136                                    // 56*56 px per image
#define APAD_POS ((size_t)N_IMG * HP * WP)          // 107648 padded positions
#define APAD_BYTES (APAD_POS * C_IN)                // 27.6 MB fp8
#define TPI 13
#define AL_GRAN 1072

__device__ __forceinline__ unsigned int sgn8(float x) {
    // fp8 e4m3fn: +1.0 = 0x38, -1.0 = 0xB8, 0 = 0x00
    return x > 0.f ? 0x38u : (x < 0.f ? 0xB8u : 0u);
}

__device__ __forceinline__ void glds16(const unsigned char* g, unsigned char* l) {
    __builtin_amdgcn_global_load_lds(
        (const __attribute__((address_space(1))) unsigned int*)g,
        (__attribute__((address_space(3))) unsigned int*)l, 16, 0, 0);
}

// ---------------------------------------------------------------------------
// Binarize x (NCHW fp32) -> zero-padded NHWC fp8 sign buffer. (unchanged)
__global__ __launch_bounds__(256) void binarize_act(
    const float* __restrict__ x, unsigned char* __restrict__ apad)
{
    int bid = blockIdx.x;
    int n = bid / HP;
    int hp = bid - n * HP;
    int tid = threadIdx.x;

    unsigned char* rowp = apad + ((size_t)(n * HP + hp) * WP) * C_IN;
    uint4 z = {0u, 0u, 0u, 0u};

    if (hp == 0 || hp == HP - 1) {                    // border rows: zero 58x256B
#pragma unroll
        for (int j = 0; j < 4; ++j) {
            int t = tid + 256 * j;                    // < 928 = 58*16
            if (t < WP * 16) {
                int w = t >> 4, g = t & 15;
                *(uint4*)(rowp + (size_t)w * C_IN + g * 16) = z;
            }
        }
        return;
    }
    int h = hp - 1;

    __shared__ unsigned int tile[C_IN * 15];          // [ci][word0..13], stride 15
    __shared__ unsigned int lds2[56 * 65];            // [w][cq0..63], stride 65

    const float* xb = x + ((size_t)n * C_IN) * GPI + h * 56;
#pragma unroll
    for (int j = 0; j < 14; ++j) {                    // 256 ch x 14 float4
        int t = tid + 256 * j;
        int ci = t / 14;
        int w4 = t - ci * 14;
        float4 v = *(const float4*)(xb + (size_t)ci * GPI + w4 * 4);
        tile[ci * 15 + w4] = sgn8(v.x) | (sgn8(v.y) << 8) |
                             (sgn8(v.z) << 16) | (sgn8(v.w) << 24);
    }
    __syncthreads();

    // Phase 2a: t = whi*256 + cq*4 + wlo ; w = whi*4+wlo ; cq = channel quad
#pragma unroll
    for (int j = 0; j < 14; ++j) {
        int t = tid + 256 * j;                        // < 3584 = 14*64*4
        int wlo = t & 3;
        int cq  = (t >> 2) & 63;
        int whi = t >> 8;
        int sh = wlo * 8;
        unsigned int r = 0;
#pragma unroll
        for (int i = 0; i < 4; ++i) {
            unsigned int v = tile[(cq * 4 + i) * 15 + whi];
            r |= ((v >> sh) & 0xFFu) << (8 * i);
        }
        lds2[(whi * 4 + wlo) * 65 + cq] = r;
    }
    __syncthreads();

    // Phase 2b: 56 w x 16 uint4 -> contiguous stores (pos w+1, c = g*16..)
#pragma unroll
    for (int j = 0; j < 4; ++j) {
        int t = tid + 256 * j;                        // < 896 = 56*16
        if (t < 896) {
            int w = t >> 4, g = t & 15;
            uint4 v;
            v.x = lds2[w * 65 + g * 4 + 0];
            v.y = lds2[w * 65 + g * 4 + 1];
            v.z = lds2[w * 65 + g * 4 + 2];
            v.w = lds2[w * 65 + g * 4 + 3];
            *(uint4*)(rowp + (size_t)(w + 1) * C_IN + g * 16) = v;
        }
    }
    if (tid < 32) {                                   // zero pad cols 0 and 57
        int g = tid & 15;
        int col = (tid >> 4) * (WP - 1);
        *(uint4*)(rowp + (size_t)col * C_IN + g * 16) = z;
    }
}

// ---------------------------------------------------------------------------
// M (O,C,3,3) fp32 -> wpk[t][o][c''] fp8 sign, t = kh*3+kw.
// NEW c-permutation within each 64-channel group so a lane's GEMM A-operand
// (its hb half, 4 ks chunks) is 32B CONTIGUOUS:
//   cc = c & 63 ; pos = (cc&8 ? 32 : 0) + (cc>>4)*8 + (cc&7)
// => bytes [hb*32 + ks*8 + b] hold channel 16ks + 8hb + b   (b = 0..7)
__global__ __launch_bounds__(256) void pack_w(
    const float* __restrict__ M, unsigned char* __restrict__ wpk)
{
    int gid = blockIdx.x * 256 + threadIdx.x;         // 16384
    int o = gid >> 6;
    int c4 = (gid & 63) << 2;                         // c4 % 4 == 0 -> same octet
    int cc = c4 & 63;
    int pos = (c4 & 0xC0) + ((cc & 8) ? 32 : 0) + ((cc >> 4) << 3) + (cc & 7);
    const float* mb = M + (size_t)(o * C_IN + c4) * 9;
#pragma unroll
    for (int t = 0; t < 9; ++t) {
        unsigned int r = sgn8(mb[t]) | (sgn8(mb[9 + t]) << 8) |
                         (sgn8(mb[18 + t]) << 16) | (sgn8(mb[27 + t]) << 24);
        *(unsigned int*)(wpk + (size_t)t * 65536 + o * C_IN + pos) = r;
    }
}

// ---------------------------------------------------------------------------
// Implicit GEMM, MX-scaled fp8 32x32x64 MFMA, 2-phase pipelined.
__global__ __launch_bounds__(256, 2) void bconv_gemm(
    const unsigned char* __restrict__ apad,
    const unsigned char* __restrict__ wpk,
    const float* __restrict__ alpha,
    float* __restrict__ out)
{
    __shared__ __align__(16) unsigned char Al[2][AL_GRAN * 16];  // 2 x 17.2 KB

    const int tid = threadIdx.x;
    const int wv = tid >> 6, lane = tid & 63;
    const int l31 = lane & 31, hb = lane >> 5;

    // XCD-bijective swizzle: grid 832 = 8 * 104
    const int hw = blockIdx.x;
    const int bid = (hw & 7) * 104 + (hw >> 3);

    const int img = bid / 26;
    const int rem = bid - img * 26;
    const int tl = rem >> 1, ot = rem & 1;
    const int g0 = tl << 8;
    const int h0 = g0 / 56, w0 = g0 - h0 * 56;
    const int o_base = ot << 7;
    const int Q0 = (img * HP + h0) * WP + w0;

    int al_pos[5], al_sl[5];
#pragma unroll
    for (int it = 0; it < 5; ++it) {
        int s = (it < 4) ? (tid + (it << 8)) : (tid + 816);
        int pos = s >> 2, gI = s & 3;
        al_pos[it] = pos;
        al_sl[it]  = ((gI - (pos >> 1)) & 3) << 4;
    }

    const int o_half  = (wv >> 1) << 6;
    const int px_half = (wv & 1) << 7;

    int pos_tab[4], pxg[4];
#pragma unroll
    for (int nt = 0; nt < 4; ++nt) {
        int px = px_half + (nt << 5) + l31;
        pxg[nt] = g0 + px;
        int pxc = (pxg[nt] < GPI) ? px : (GPI - 1 - g0);
        pos_tab[nt] = pxc + 2 * ((w0 + pxc) / 56);
    }

    floatx16 acc[2][4] = {};

    // ---- prologue: stage step 0 (kh=0, c0=0) into Al[0]
    {
        const int plim = (int)APAD_POS - 1 - Q0;
        const unsigned char* asrc = apad + ((size_t)Q0 << 8);
#pragma unroll
        for (int it = 0; it < 5; ++it) {
            int p = al_pos[it] < plim ? al_pos[it] : plim;
            int dst = (it < 4) ? ((it << 8) + (wv << 6)) : (816 + (wv << 6));
            glds16(asrc + ((size_t)p << 8) + al_sl[it], &Al[0][(size_t)dst << 4]);
        }
    }
    __syncthreads();

    int cur = 0;
    for (int t = 0; t < 12; ++t) {
        const int kh = t >> 2, c0 = (t & 3) << 6;

        // ---- W fragments for THIS step: 12 dwordx4, L2-resident, 48 VGPR
        union WF { uint4 q[2]; intx8 v; };
        WF wf[2][3];
        {
            const unsigned char* wb = wpk + (size_t)(kh * 3) * 65536 +
                                      ((size_t)o_base << 8) + c0 + (hb << 5);
#pragma unroll
            for (int mt = 0; mt < 2; ++mt)
#pragma unroll
                for (int kw = 0; kw < 3; ++kw) {
                    const unsigned char* p = wb + (size_t)kw * 65536 +
                        ((size_t)(o_half + (mt << 5) + l31) << 8);
                    wf[mt][kw].q[0] = *(const uint4*)(p);
                    wf[mt][kw].q[1] = *(const uint4*)(p + 16);
                }
        }

        // ---- stage step t+1 into Al[cur^1] (in flight during compute)
        if (t < 11) {
            const int t1 = t + 1;
            const int kh1 = t1 >> 2, c01 = (t1 & 3) << 6;
            const int rowbase1 = Q0 + kh1 * WP;
            const int plim1 = (int)APAD_POS - 1 - rowbase1;
            const unsigned char* asrc1 = apad + (((size_t)rowbase1 << 8) + c01);
#pragma unroll
            for (int it = 0; it < 5; ++it) {
                int p = al_pos[it] < plim1 ? al_pos[it] : plim1;
                int dst = (it < 4) ? ((it << 8) + (wv << 6)) : (816 + (wv << 6));
                glds16(asrc1 + ((size_t)p << 8) + al_sl[it],
                       &Al[cur ^ 1][(size_t)dst << 4]);
            }
        }

        // ---- compute from Al[cur] + wf regs
        const unsigned char* AlC = &Al[cur][0];
#pragma unroll
        for (int kw = 0; kw < 3; ++kw) {
#pragma unroll
            for (int nt = 0; nt < 4; ++nt) {
                int pos = pos_tab[nt] + kw;
                union F { long l[4]; intx8 v; } bf;
#pragma unroll
                for (int ks = 0; ks < 4; ++ks) {
                    int g = (pos << 2) + ((ks + (pos >> 1)) & 3);
                    bf.l[ks] = *(const long*)&AlC[(size_t)(g << 4) + (hb << 3)];
                }
#pragma unroll
                for (int mt = 0; mt < 2; ++mt)
                    acc[mt][nt] = __builtin_amdgcn_mfma_scale_f32_32x32x64_f8f6f4(
                        wf[mt][kw].v, bf.v, acc[mt][nt],
                        0, 0,                      // cbsz=fp8(e4m3), blgp=fp8(e4m3)
                        0, 0x7F7F7F7F,             // opsel_a, scale_a = 1.0
                        0, 0x7F7F7F7F);            // opsel_b, scale_b = 1.0
            }
        }

        __syncthreads();                               // one barrier per step
        cur ^= 1;
    }

#pragma unroll
    for (int mt = 0; mt < 2; ++mt) {
#pragma unroll
        for (int r = 0; r < 16; ++r) {
            int o_loc = o_half + (mt << 5) + (r & 3) + ((r >> 2) << 3) + (hb << 2);
            int o_g = o_base + o_loc;
            float a = alpha[o_g];
            float* ob = out + ((size_t)(img * O_OUT + o_g)) * GPI;
#pragma unroll
            for (int nt = 0; nt < 4; ++nt) {
                if (pxg[nt] < GPI) ob[pxg[nt]] = acc[mt][nt][r] * a;
            }
        }
    }
}

// ---------------------------------------------------------------------------
extern "C" void kernel_launch(void* const* d_in, const int* in_sizes, int n_in,
                              void* d_out, int out_size, void* d_ws, size_t ws_size,
                              hipStream_t stream) {
    const float* x     = (const float*)d_in[0];
    const float* M     = (const float*)d_in[1];
    const float* alpha = (const float*)d_in[2];
    float* out = (float*)d_out;

    unsigned char* apad = (unsigned char*)d_ws;
    unsigned char* wpk  = apad + APAD_BYTES;

    binarize_act<<<dim3(N_IMG * HP), dim3(256), 0, stream>>>(x, apad);
    pack_w<<<dim3(64), dim3(256), 0, stream>>>(M, wpk);
    bconv_gemm<<<dim3(N_IMG * TPI * 2), dim3(256), 0, stream>>>(apad, wpk, alpha, out);
}

// Round 4
// 284.296 us; speedup vs baseline: 1.0536x; 1.0536x over previous
//
#include <hip/hip_runtime.h>
#include <stdint.h>

// BinarizeConv2dSDP: out = conv3x3(sign(x), sign(M), pad=1) * Alpha[o]
// R8: fix R7's W-load regression + bf LDS conflicts.
//   - wpk repacked into wave-contiguous 2KB fragments [kh,c0q][kw][oblk][lane*32]:
//     wf loads are 1KB/instr contiguous streams (16x fewer L2 transactions).
//   - Al rows 64B, 4x16B chunks XOR-swizzled at slot q ^ ((pos>>1)&3), applied
//     on the glds16 SOURCE address (LDS dest linear); bf = 2x ds_read_b128 at
//     structural-minimum bank occupancy (8 cols/instr).
//   - byte<->channel map linear both sides: A,B byte (hb,u,b) = c0+32hb+16u+b
//     (symmetric placement => exact, same argument as verified R6/R7).
//   - Al double-buffer, one barrier/step, XCD swizzle kept from R7.
//   - pack_w: 256 blocks x 64 threads (latency-bound scatter, more CUs).
// binarize_act unchanged (verified absmax 0.0).

typedef __attribute__((ext_vector_type(16))) float floatx16;
typedef __attribute__((ext_vector_type(8)))  int   intx8;

#define N_IMG 32
#define C_IN  256
#define O_OUT 256
#define HP 58
#define WP 58
#define GPI 3136                                    // 56*56 px per image
#define APAD_POS ((size_t)N_IMG * HP * WP)          // 107648 padded positions
#define APAD_BYTES (APAD_POS * C_IN)                // 27.6 MB fp8
#define TPI 13
#define AL_GRAN 1072
#define WPK_STEP 49152                              // 3 kw * 8 oblk * 2048 B

__device__ __forceinline__ unsigned int sgn8(float x) {
    // fp8 e4m3fn: +1.0 = 0x38, -1.0 = 0xB8, 0 = 0x00
    return x > 0.f ? 0x38u : (x < 0.f ? 0xB8u : 0u);
}

__device__ __forceinline__ void glds16(const unsigned char* g, unsigned char* l) {
    __builtin_amdgcn_global_load_lds(
        (const __attribute__((address_space(1))) unsigned int*)g,
        (__attribute__((address_space(3))) unsigned int*)l, 16, 0, 0);
}

// ---------------------------------------------------------------------------
// Binarize x (NCHW fp32) -> zero-padded NHWC fp8 sign buffer. (unchanged)
__global__ __launch_bounds__(256) void binarize_act(
    const float* __restrict__ x, unsigned char* __restrict__ apad)
{
    int bid = blockIdx.x;
    int n = bid / HP;
    int hp = bid - n * HP;
    int tid = threadIdx.x;

    unsigned char* rowp = apad + ((size_t)(n * HP + hp) * WP) * C_IN;
    uint4 z = {0u, 0u, 0u, 0u};

    if (hp == 0 || hp == HP - 1) {                    // border rows: zero 58x256B
#pragma unroll
        for (int j = 0; j < 4; ++j) {
            int t = tid + 256 * j;                    // < 928 = 58*16
            if (t < WP * 16) {
                int w = t >> 4, g = t & 15;
                *(uint4*)(rowp + (size_t)w * C_IN + g * 16) = z;
            }
        }
        return;
    }
    int h = hp - 1;

    __shared__ unsigned int tile[C_IN * 15];          // [ci][word0..13], stride 15
    __shared__ unsigned int lds2[56 * 65];            // [w][cq0..63], stride 65

    const float* xb = x + ((size_t)n * C_IN) * GPI + h * 56;
#pragma unroll
    for (int j = 0; j < 14; ++j) {                    // 256 ch x 14 float4
        int t = tid + 256 * j;
        int ci = t / 14;
        int w4 = t - ci * 14;
        float4 v = *(const float4*)(xb + (size_t)ci * GPI + w4 * 4);
        tile[ci * 15 + w4] = sgn8(v.x) | (sgn8(v.y) << 8) |
                             (sgn8(v.z) << 16) | (sgn8(v.w) << 24);
    }
    __syncthreads();

    // Phase 2a: t = whi*256 + cq*4 + wlo ; w = whi*4+wlo ; cq = channel quad
#pragma unroll
    for (int j = 0; j < 14; ++j) {
        int t = tid + 256 * j;                        // < 3584 = 14*64*4
        int wlo = t & 3;
        int cq  = (t >> 2) & 63;
        int whi = t >> 8;
        int sh = wlo * 8;
        unsigned int r = 0;
#pragma unroll
        for (int i = 0; i < 4; ++i) {
            unsigned int v = tile[(cq * 4 + i) * 15 + whi];
            r |= ((v >> sh) & 0xFFu) << (8 * i);
        }
        lds2[(whi * 4 + wlo) * 65 + cq] = r;
    }
    __syncthreads();

    // Phase 2b: 56 w x 16 uint4 -> contiguous stores (pos w+1, c = g*16..)
#pragma unroll
    for (int j = 0; j < 4; ++j) {
        int t = tid + 256 * j;                        // < 896 = 56*16
        if (t < 896) {
            int w = t >> 4, g = t & 15;
            uint4 v;
            v.x = lds2[w * 65 + g * 4 + 0];
            v.y = lds2[w * 65 + g * 4 + 1];
            v.z = lds2[w * 65 + g * 4 + 2];
            v.w = lds2[w * 65 + g * 4 + 3];
            *(uint4*)(rowp + (size_t)(w + 1) * C_IN + g * 16) = v;
        }
    }
    if (tid < 32) {                                   // zero pad cols 0 and 57
        int g = tid & 15;
        int col = (tid >> 4) * (WP - 1);
        *(uint4*)(rowp + (size_t)col * C_IN + g * 16) = z;
    }
}

// ---------------------------------------------------------------------------
// M (O,C,3,3) fp32 -> wpk fragments: [kh*4+c0q][kw][oblk] 2KB blocks laid out
// in GEMM lane order: byte (hb,u,b) at hb*1024 + (o&31)*32 + (c&31), where
// channel c = c0 + 32*hb + 16*u + b  (linear within the 64-ch window).
__global__ __launch_bounds__(64) void pack_w(
    const float* __restrict__ M, unsigned char* __restrict__ wpk)
{
    int gid = blockIdx.x * 64 + threadIdx.x;          // 16384 = 256 blk x 64
    int o = gid >> 6;
    int c4 = (gid & 63) << 2;
    const float* mb = M + (size_t)(o * C_IN + c4) * 9;
    int oblk = o >> 5;
    int c0q = c4 >> 6;
    int dst_in = ((c4 >> 5) & 1) * 1024 + (o & 31) * 32 + (c4 & 31);
#pragma unroll
    for (int t = 0; t < 9; ++t) {
        int kh = t / 3, kw = t - 3 * (t / 3);
        unsigned int r = sgn8(mb[t]) | (sgn8(mb[9 + t]) << 8) |
                         (sgn8(mb[18 + t]) << 16) | (sgn8(mb[27 + t]) << 24);
        size_t frag = (size_t)(kh * 4 + c0q) * WPK_STEP +
                      (size_t)(kw * 8 + oblk) * 2048;
        *(unsigned int*)(wpk + frag + dst_in) = r;
    }
}

// ---------------------------------------------------------------------------
// Implicit GEMM, MX-scaled fp8 32x32x64 MFMA, 2-phase pipelined.
__global__ __launch_bounds__(256, 2) void bconv_gemm(
    const unsigned char* __restrict__ apad,
    const unsigned char* __restrict__ wpk,
    const float* __restrict__ alpha,
    float* __restrict__ out)
{
    __shared__ __align__(16) unsigned char Al[2][AL_GRAN * 16];  // 2 x 16.75 KB

    const int tid = threadIdx.x;
    const int wv = tid >> 6, lane = tid & 63;
    const int l31 = lane & 31, hb = lane >> 5;

    // XCD-bijective swizzle: grid 832 = 8 * 104
    const int hw = blockIdx.x;
    const int bid = (hw & 7) * 104 + (hw >> 3);

    const int img = bid / 26;
    const int rem = bid - img * 26;
    const int tl = rem >> 1, ot = rem & 1;
    const int g0 = tl << 8;
    const int h0 = g0 / 56, w0 = g0 - h0 * 56;
    const int o_base = ot << 7;
    const int Q0 = (img * HP + h0) * WP + w0;

    // staging tables: gran s -> row pos = s>>2, sub gI = s&3;
    // SOURCE chunk = gI ^ ((pos>>1)&3)  (XOR swizzle on global side; LDS linear)
    int al_pos[5], al_sl[5];
#pragma unroll
    for (int it = 0; it < 5; ++it) {
        int s = (it < 4) ? (tid + (it << 8)) : (tid + 816);
        int pos = s >> 2, gI = s & 3;
        al_pos[it] = pos;
        al_sl[it]  = ((gI ^ ((pos >> 1) & 3)) << 4);
    }

    const int o_half  = (wv >> 1) << 6;
    const int px_half = (wv & 1) << 7;
    const int oblk0   = (ot << 2) + ((wv >> 1) << 1);   // + mt -> global o>>5

    int pos_tab[4], pxg[4];
#pragma unroll
    for (int nt = 0; nt < 4; ++nt) {
        int px = px_half + (nt << 5) + l31;
        pxg[nt] = g0 + px;
        int pxc = (pxg[nt] < GPI) ? px : (GPI - 1 - g0);
        pos_tab[nt] = pxc + 2 * ((w0 + pxc) / 56);
    }

    floatx16 acc[2][4] = {};

    // ---- prologue: stage step 0 (kh=0, c0=0) into Al[0]
    {
        const int plim = (int)APAD_POS - 1 - Q0;
        const unsigned char* asrc = apad + ((size_t)Q0 << 8);
#pragma unroll
        for (int it = 0; it < 5; ++it) {
            int p = al_pos[it] < plim ? al_pos[it] : plim;
            int dst = (it < 4) ? ((it << 8) + (wv << 6)) : (816 + (wv << 6));
            glds16(asrc + ((size_t)p << 8) + al_sl[it], &Al[0][(size_t)dst << 4]);
        }
    }
    __syncthreads();

    int cur = 0;
    for (int t = 0; t < 12; ++t) {                    // t = kh*4 + c0q
        // ---- W fragments for THIS step: 12 dwordx4, wave-contiguous 1KB/instr
        union WF { uint4 q[2]; intx8 v; };
        WF wf[2][3];
        {
            const unsigned char* wb = wpk + (size_t)t * WPK_STEP + ((size_t)lane << 5);
#pragma unroll
            for (int mt = 0; mt < 2; ++mt)
#pragma unroll
                for (int kw = 0; kw < 3; ++kw) {
                    const unsigned char* p = wb + (size_t)((kw << 3) + oblk0 + mt) * 2048;
                    wf[mt][kw].q[0] = *(const uint4*)(p);
                    wf[mt][kw].q[1] = *(const uint4*)(p + 16);
                }
        }

        // ---- stage step t+1 into Al[cur^1] (in flight during compute)
        if (t < 11) {
            const int t1 = t + 1;
            const int kh1 = t1 >> 2, c01 = (t1 & 3) << 6;
            const int rowbase1 = Q0 + kh1 * WP;
            const int plim1 = (int)APAD_POS - 1 - rowbase1;
            const unsigned char* asrc1 = apad + (((size_t)rowbase1 << 8) + c01);
#pragma unroll
            for (int it = 0; it < 5; ++it) {
                int p = al_pos[it] < plim1 ? al_pos[it] : plim1;
                int dst = (it < 4) ? ((it << 8) + (wv << 6)) : (816 + (wv << 6));
                glds16(asrc1 + ((size_t)p << 8) + al_sl[it],
                       &Al[cur ^ 1][(size_t)dst << 4]);
            }
        }

        // ---- compute from Al[cur] + wf regs
        const unsigned char* AlC = &Al[cur][0];
#pragma unroll
        for (int kw = 0; kw < 3; ++kw) {
#pragma unroll
            for (int nt = 0; nt < 4; ++nt) {
                int pos = pos_tab[nt] + kw;
                int rb = pos << 6;
                int m3 = (pos >> 1) & 3;
                union F { uint4 q[2]; intx8 v; } bf;
                bf.q[0] = *(const uint4*)&AlC[rb + ((((hb << 1))     ^ m3) << 4)];
                bf.q[1] = *(const uint4*)&AlC[rb + ((((hb << 1) | 1) ^ m3) << 4)];
#pragma unroll
                for (int mt = 0; mt < 2; ++mt)
                    acc[mt][nt] = __builtin_amdgcn_mfma_scale_f32_32x32x64_f8f6f4(
                        wf[mt][kw].v, bf.v, acc[mt][nt],
                        0, 0,                      // cbsz=fp8(e4m3), blgp=fp8(e4m3)
                        0, 0x7F7F7F7F,             // opsel_a, scale_a = 1.0
                        0, 0x7F7F7F7F);            // opsel_b, scale_b = 1.0
            }
        }

        __syncthreads();                               // one barrier per step
        cur ^= 1;
    }

#pragma unroll
    for (int mt = 0; mt < 2; ++mt) {
#pragma unroll
        for (int r = 0; r < 16; ++r) {
            int o_loc = o_half + (mt << 5) + (r & 3) + ((r >> 2) << 3) + (hb << 2);
            int o_g = o_base + o_loc;
            float a = alpha[o_g];
            float* ob = out + ((size_t)(img * O_OUT + o_g)) * GPI;
#pragma unroll
            for (int nt = 0; nt < 4; ++nt) {
                if (pxg[nt] < GPI) ob[pxg[nt]] = acc[mt][nt][r] * a;
            }
        }
    }
}

// ---------------------------------------------------------------------------
extern "C" void kernel_launch(void* const* d_in, const int* in_sizes, int n_in,
                              void* d_out, int out_size, void* d_ws, size_t ws_size,
                              hipStream_t stream) {
    const float* x     = (const float*)d_in[0];
    const float* M     = (const float*)d_in[1];
    const float* alpha = (const float*)d_in[2];
    float* out = (float*)d_out;

    unsigned char* apad = (unsigned char*)d_ws;
    unsigned char* wpk  = apad + APAD_BYTES;

    binarize_act<<<dim3(N_IMG * HP), dim3(256), 0, stream>>>(x, apad);
    pack_w<<<dim3(256), dim3(64), 0, stream>>>(M, wpk);
    bconv_gemm<<<dim3(N_IMG * TPI * 2), dim3(256), 0, stream>>>(apad, wpk, alpha, out);
}